// Round 1
// baseline (224.362 us; speedup 1.0000x reference)
//
#include <hip/hip_runtime.h>
#include <math.h>

#define NROWS 16384
#define DIM   16
#define KC    1024          // K-chunk staged in LDS (64 KB)
#define WGT   512           // threads per workgroup (8 waves)
#define RPW   4             // rows per wave
#define RPWG  32            // rows per workgroup (8 waves * 4)

static __device__ __forceinline__ void fma4(float4& a, float s, const float4& b) {
    a.x = fmaf(s, b.x, a.x);
    a.y = fmaf(s, b.y, a.y);
    a.z = fmaf(s, b.z, a.z);
    a.w = fmaf(s, b.w, a.w);
}

static __device__ __forceinline__ float dot4(const float4& a) {
    return a.x * a.x + a.y * a.y + a.z * a.z + a.w * a.w;
}

static __device__ __forceinline__ float4 scale4(const float4& a, float s) {
    return make_float4(a.x * s, a.y * s, a.z * s, a.w * s);
}

// ---------------- Kernel 1: xt = logmap0(x) ----------------
__global__ void hyp_logmap0(const float* __restrict__ x, float* __restrict__ xt) {
    int row = blockIdx.x * blockDim.x + threadIdx.x;   // grid = NROWS threads
    const float4* src = (const float4*)(x + (size_t)row * DIM);
    float4 q0 = src[0], q1 = src[1], q2 = src[2], q3 = src[3];
    float n2 = dot4(q0) + dot4(q1) + dot4(q2) + dot4(q3);
    float n  = fmaxf(sqrtf(n2), 1e-15f);
    float arg = fminf(n, 1.0f - 1e-7f);
    float f = atanhf(arg) / n;
    float4* dst = (float4*)(xt + (size_t)row * DIM);
    dst[0] = scale4(q0, f);
    dst[1] = scale4(q1, f);
    dst[2] = scale4(q2, f);
    dst[3] = scale4(q3, f);
}

// ---------------- Kernel 2: out = proj(expmap0(adj @ xt)) ----------------
__global__ __launch_bounds__(WGT, 4) void hyp_agg(
        const float* __restrict__ adj, const float* __restrict__ xt,
        float* __restrict__ out) {
    // xt chunk staged as 4 quad-planes: planes[j][k] = float4 quad j of xt row k.
    // A wave reading planes[j][base+lane] is 16 B/lane contiguous -> conflict-free b128.
    __shared__ float4 planes[4][KC];

    const int tid  = threadIdx.x;
    const int lane = tid & 63;
    const int wave = tid >> 6;
    const int rowBase = blockIdx.x * RPWG + wave * RPW;

    const float* a0 = adj + (size_t)(rowBase + 0) * NROWS;
    const float* a1 = adj + (size_t)(rowBase + 1) * NROWS;
    const float* a2 = adj + (size_t)(rowBase + 2) * NROWS;
    const float* a3 = adj + (size_t)(rowBase + 3) * NROWS;

    float4 acc[RPW][4];
#pragma unroll
    for (int r = 0; r < RPW; ++r)
#pragma unroll
        for (int j = 0; j < 4; ++j)
            acc[r][j] = make_float4(0.f, 0.f, 0.f, 0.f);

    for (int kc = 0; kc < NROWS; kc += KC) {
        __syncthreads();
        // stage xt[kc:kc+KC] -> quad planes (coalesced global, contiguous LDS writes)
#pragma unroll
        for (int kk = tid; kk < KC; kk += WGT) {
            const float4* src = (const float4*)(xt + (size_t)(kc + kk) * DIM);
            float4 q0 = src[0], q1 = src[1], q2 = src[2], q3 = src[3];
            planes[0][kk] = q0;
            planes[1][kk] = q1;
            planes[2][kk] = q2;
            planes[3][kk] = q3;
        }
        __syncthreads();

#pragma unroll 2
        for (int it = 0; it < KC / 64; ++it) {
            const int kk = it * 64 + lane;
            const int k  = kc + kk;
            // adj: streaming, zero reuse -> nontemporal; coalesced across lanes
            float v0 = __builtin_nontemporal_load(a0 + k);
            float v1 = __builtin_nontemporal_load(a1 + k);
            float v2 = __builtin_nontemporal_load(a2 + k);
            float v3 = __builtin_nontemporal_load(a3 + k);
            float4 q0 = planes[0][kk];
            float4 q1 = planes[1][kk];
            float4 q2 = planes[2][kk];
            float4 q3 = planes[3][kk];
            fma4(acc[0][0], v0, q0); fma4(acc[0][1], v0, q1);
            fma4(acc[0][2], v0, q2); fma4(acc[0][3], v0, q3);
            fma4(acc[1][0], v1, q0); fma4(acc[1][1], v1, q1);
            fma4(acc[1][2], v1, q2); fma4(acc[1][3], v1, q3);
            fma4(acc[2][0], v2, q0); fma4(acc[2][1], v2, q1);
            fma4(acc[2][2], v2, q2); fma4(acc[2][3], v2, q3);
            fma4(acc[3][0], v3, q0); fma4(acc[3][1], v3, q1);
            fma4(acc[3][2], v3, q2); fma4(acc[3][3], v3, q3);
        }
    }

    // cross-lane butterfly reduce (lanes split K); all indices compile-time
#pragma unroll
    for (int r = 0; r < RPW; ++r) {
#pragma unroll
        for (int j = 0; j < 4; ++j) {
            float4 v = acc[r][j];
#pragma unroll
            for (int m = 1; m < 64; m <<= 1) {
                v.x += __shfl_xor(v.x, m, 64);
                v.y += __shfl_xor(v.y, m, 64);
                v.z += __shfl_xor(v.z, m, 64);
                v.w += __shfl_xor(v.w, m, 64);
            }
            acc[r][j] = v;
        }
    }

    // epilogue: expmap0 + proj; all lanes compute (uniform), lane 0 stores
#pragma unroll
    for (int r = 0; r < RPW; ++r) {
        float4 s0 = acc[r][0], s1 = acc[r][1], s2 = acc[r][2], s3 = acc[r][3];
        float n2 = dot4(s0) + dot4(s1) + dot4(s2) + dot4(s3);
        float n  = fmaxf(sqrtf(n2), 1e-15f);
        float t  = tanhf(n);
        float fac = t / n;                        // expmap0 factor
        float ny = fmaxf(sqrtf(n2) * fac, 1e-15f); // ||y||
        const float MAX_NORM = 1.0f - 1e-5f;
        float sc = (ny > MAX_NORM) ? (MAX_NORM / ny) : 1.0f;
        float tot = fac * sc;
        if (lane == 0) {
            float4* dst = (float4*)(out + (size_t)(rowBase + r) * DIM);
            dst[0] = scale4(s0, tot);
            dst[1] = scale4(s1, tot);
            dst[2] = scale4(s2, tot);
            dst[3] = scale4(s3, tot);
        }
    }
}

extern "C" void kernel_launch(void* const* d_in, const int* in_sizes, int n_in,
                              void* d_out, int out_size, void* d_ws, size_t ws_size,
                              hipStream_t stream) {
    const float* x   = (const float*)d_in[0];   // [16384, 16]
    const float* adj = (const float*)d_in[1];   // [16384, 16384]
    float* out = (float*)d_out;                 // [16384, 16]
    float* xt  = (float*)d_ws;                  // [16384, 16] scratch (1 MiB)

    hipLaunchKernelGGL(hyp_logmap0, dim3(NROWS / 256), dim3(256), 0, stream, x, xt);
    hipLaunchKernelGGL(hyp_agg, dim3(NROWS / RPWG), dim3(WGT), 0, stream, adj, xt, out);
}